// Round 10
// baseline (1011.942 us; speedup 1.0000x reference)
//
#include <hip/hip_runtime.h>

// Seq2Seq LSTM (enc 512 + dec 256 steps), H=50, B=2048, in/out dim 1.
//
// Round-10: MFMA reformulation. Rounds 1-9 proved the register allocator
// always parks long-lived per-lane weight arrays in AGPRs, and gfx950 VALU
// cannot read AGPR operands -> a v_accvgpr_read per FMA (the persistent
// ~2x overhead). MFMA *can* read AGPRs natively, so weights-as-MFMA-B-frags
// makes AGPR residence free.
//
// Per step, per block (batch tile MB=8): Gates[8x256] = H[8x64]@Whh^T[64x256]
// via mfma_f32_16x16x32_bf16. fp32 accuracy recovered with 3-way bf16 splits
// (hi/mid/lo; rep error 2^-24) of both W and h, keeping the 6 largest cross
// terms -> 6 MFMAs per (n-tile,k-tile). Block = 8 waves; wave w owns gate
// w>>1, units (w&1)*32..+32 (2 n-tiles x 2 k-tiles x 3 splits = 12 B-frags).
// Grid = 256 blocks x 512 thr = 2 waves/SIMD on all 256 CUs.
//
// Step = [GEMM phase: A-frags from LDS, 24 MFMA, sigmoid/tanh, activated
// gates -> gact LDS] barrier [CELL phase: thread (w,lane) owns cell
// (b=w, u=lane): c,h in regs; h re-split to bf16 A-frag layout in LDS;
// decoder: fc butterfly -> y -> xbuf + out] barrier.
//
// Fragment layouts (m89/m91-verified + AMD matrix calculator):
//   A[m=lane&15][k=(lane>>4)*8+j]  (short8, j = elem index)
//   B[n=lane&15][k=(lane>>4)*8+j]
//   D col(n)=lane&15, row(m)=(lane>>4)*4+reg

#define HID 50
#define SEQ 512
#define TGT 256
#define MB  8
#define UP  64
#define L2E 1.44269504088896341f

typedef __attribute__((ext_vector_type(8))) short short8;
typedef __attribute__((ext_vector_type(4))) float f32x4;

__device__ __forceinline__ unsigned short f2bf(float f) {   // RNE fp32->bf16
    unsigned u = __float_as_uint(f);
    return (unsigned short)((u + 0x7fffu + ((u >> 16) & 1u)) >> 16);
}
__device__ __forceinline__ float bf2f(unsigned short b) {
    return __uint_as_float(((unsigned)b) << 16);
}
__device__ __forceinline__ float sigm2(float a) {
    return __builtin_amdgcn_rcpf(1.0f + __builtin_amdgcn_exp2f(-L2E * a));
}
__device__ __forceinline__ float tanh2(float a) {
    return fmaf(2.0f,
        __builtin_amdgcn_rcpf(1.0f + __builtin_amdgcn_exp2f(-2.0f * L2E * a)),
        -1.0f);
}

#define MFMA(A, B, C) __builtin_amdgcn_mfma_f32_16x16x32_bf16((A), (B), (C), 0, 0, 0)

// hf: h bf16-splits in A-frag order. Block (s,kt,lgrp) = 16 lanes x 8 bf16,
// padded to 136 shorts (272B: keeps 16B alignment, rotates banks by 4).
#define HF_IDX(s, kt, qg, il, j) ((((s) * 2 + (kt)) * 4 + (qg)) * 136 + (il) * 8 + (j))

// One GEMM phase. XSRC = 16-float x buffer (batches 0..7 real, 8..15 zero).
#define GSTEP(XSRC)                                                          \
    {                                                                        \
        f32x4 x4 = ((const f32x4*)(XSRC))[lane >> 4];                        \
        short8 Af[2][3];                                                     \
        _Pragma("unroll")                                                    \
        for (int kt = 0; kt < 2; ++kt)                                       \
            _Pragma("unroll")                                                \
            for (int s = 0; s < 3; ++s)                                      \
                Af[kt][s] = *(const short8*)(hf + HF_IDX(s, kt, (lane >> 4), (lane & 15), 0)); \
        _Pragma("unroll")                                                    \
        for (int tt = 0; tt < 2; ++tt) {                                     \
            f32x4 a0, a1;                                                    \
            _Pragma("unroll")                                                \
            for (int r = 0; r < 4; ++r) {                                    \
                a0[r] = fmaf(wxv[tt], x4[r], bbv[tt]);                       \
                a1[r] = 0.0f;                                                \
            }                                                                \
            a0 = MFMA(Af[0][0], Bf[tt][0][0], a0);                           \
            a0 = MFMA(Af[0][0], Bf[tt][0][1], a0);                           \
            a0 = MFMA(Af[0][1], Bf[tt][0][0], a0);                           \
            a0 = MFMA(Af[0][1], Bf[tt][0][1], a0);                           \
            a0 = MFMA(Af[0][0], Bf[tt][0][2], a0);                           \
            a0 = MFMA(Af[0][2], Bf[tt][0][0], a0);                           \
            a1 = MFMA(Af[1][0], Bf[tt][1][0], a1);                           \
            a1 = MFMA(Af[1][0], Bf[tt][1][1], a1);                           \
            a1 = MFMA(Af[1][1], Bf[tt][1][0], a1);                           \
            a1 = MFMA(Af[1][1], Bf[tt][1][1], a1);                           \
            a1 = MFMA(Af[1][0], Bf[tt][1][2], a1);                           \
            a1 = MFMA(Af[1][2], Bf[tt][1][0], a1);                           \
            f32x4 g = a0 + a1;                                               \
            _Pragma("unroll")                                                \
            for (int r = 0; r < 4; ++r) {                                    \
                float av = g[r];                                             \
                float actv = (gw == 2) ? tanh2(av) : sigm2(av);              \
                if ((lane >> 4) < 2) {                                       \
                    int bb_ = (lane >> 4) * 4 + r;                           \
                    int uu  = ub + tt * 16 + (lane & 15);                    \
                    gact[(bb_ * UP + uu) * 4 + gw] = actv;                   \
                }                                                            \
            }                                                                \
        }                                                                    \
    }

// Cell phase core: update c, compute hv, write bf16 splits to hf.
#define CSTEP_COMMON                                                         \
    float4 g4 = *(const float4*)(gact + (w * UP + lane) * 4);                \
    c = fmaf(g4.y, c, g4.x * g4.z);                                          \
    float hv = g4.w * tanh2(c);                                              \
    if (lane >= HID) hv = 0.0f;                                              \
    {                                                                        \
        unsigned short p0 = f2bf(hv);                                        \
        float rr = hv - bf2f(p0);                                            \
        unsigned short p1 = f2bf(rr);                                        \
        float rr2 = rr - bf2f(p1);                                           \
        unsigned short p2 = f2bf(rr2);                                       \
        int kt = lane >> 5, qg = (lane & 31) >> 3, jj = lane & 7;            \
        hf[HF_IDX(0, kt, qg, w, jj)] = (short)p0;                            \
        hf[HF_IDX(1, kt, qg, w, jj)] = (short)p1;                            \
        hf[HF_IDX(2, kt, qg, w, jj)] = (short)p2;                            \
    }

extern "C" __global__ void __launch_bounds__(512, 2)
seq2seq_kernel(const float* __restrict__ src,
               const float* __restrict__ eWih, const float* __restrict__ eWhh,
               const float* __restrict__ eBih, const float* __restrict__ eBhh,
               const float* __restrict__ dWih, const float* __restrict__ dWhh,
               const float* __restrict__ dBih, const float* __restrict__ dBhh,
               const float* __restrict__ fcW, const float* __restrict__ fcB,
               float* __restrict__ out) {
    const int tid  = threadIdx.x;       // 0..511
    const int lane = tid & 63;
    const int w    = tid >> 6;          // wave 0..7
    const int gw   = w >> 1;            // gate id (i,f,g,o)
    const int ub   = (w & 1) * 32;      // unit base of this wave's n-tiles
    const int b0   = blockIdx.x * MB;   // batch base

    __shared__ __align__(16) short hf[3264];          // 3 splits x 2 kt x 4 grp x 136
    __shared__ __align__(16) float gact[MB * UP * 4]; // [b][u][gate]
    __shared__ __align__(16) float srcT[SEQ * 16];    // [t][b pad 16]
    __shared__ __align__(16) float xbuf[16];          // decoder x (pad 16)

    for (int i = tid; i < 3264; i += 512) hf[i] = 0;
    for (int i = tid; i < SEQ * 16; i += 512) {
        int t = i >> 4, bi = i & 15;
        srcT[i] = (bi < MB) ? src[(size_t)(b0 + bi) * SEQ + t] : 0.0f;
    }

    float c = 0.0f;                                    // cell (b=w, u=lane)
    const float fcw = (lane < HID) ? fcW[lane] : 0.0f;
    const float fb  = fcB[0];

    short8 Bf[2][2][3];                 // [n-tile][k-tile][split] weight frags
    float bbv[2], wxv[2];

    auto loadW = [&](const float* Wih, const float* Whh,
                     const float* Bih, const float* Bhh) {
#pragma unroll
        for (int tt = 0; tt < 2; ++tt) {
            int un = ub + tt * 16 + (lane & 15);       // unit of my n-col
            bool nv = (un < HID);
            int row = gw * HID + (nv ? un : 0);        // PyTorch row g*50+u
            bbv[tt] = nv ? (Bih[row] + Bhh[row]) : 0.0f;
            wxv[tt] = nv ? Wih[row] : 0.0f;
#pragma unroll
            for (int kt = 0; kt < 2; ++kt) {
                short8 s0, s1, s2;
#pragma unroll
                for (int j = 0; j < 8; ++j) {
                    int kk = kt * 32 + (lane >> 4) * 8 + j;
                    float wv = (nv && kk < HID) ? Whh[(size_t)row * HID + kk] : 0.0f;
                    unsigned short q0 = f2bf(wv);
                    float r1 = wv - bf2f(q0);
                    unsigned short q1 = f2bf(r1);
                    float r2 = r1 - bf2f(q1);
                    unsigned short q2 = f2bf(r2);
                    s0[j] = (short)q0; s1[j] = (short)q1; s2[j] = (short)q2;
                }
                Bf[tt][kt][0] = s0; Bf[tt][kt][1] = s1; Bf[tt][kt][2] = s2;
            }
        }
    };

    // ---------------- encoder: 512 steps ----------------
    loadW(eWih, eWhh, eBih, eBhh);
    __syncthreads();                    // hf/srcT init visible
    for (int t = 0; t < SEQ; ++t) {
        GSTEP(srcT + t * 16)
        __syncthreads();                // gact visible
        { CSTEP_COMMON }
        __syncthreads();                // hf visible
    }

    // ---------------- decoder: 256 steps ----------------
    loadW(dWih, dWhh, dBih, dBhh);
    if (tid < 16) xbuf[tid] = 0.0f;     // decoder_input = zeros (8..15 pad)
    __syncthreads();
    float* ob = out + (size_t)(b0 + w) * TGT;
    for (int t = 0; t < TGT; ++t) {
        GSTEP(xbuf)
        __syncthreads();
        {
            CSTEP_COMMON
            float p = fcw * hv;         // fc: y[b=w] = sum_u fcW[u]*h[u]
#pragma unroll
            for (int off = 32; off > 0; off >>= 1) p += __shfl_xor(p, off, 64);
            float y = p + fb;
            if (lane == 0) { xbuf[w] = y; ob[t] = y; }
        }
        __syncthreads();
    }
}

extern "C" void kernel_launch(void* const* d_in, const int* in_sizes, int n_in,
                              void* d_out, int out_size, void* d_ws, size_t ws_size,
                              hipStream_t stream) {
    const float* src  = (const float*)d_in[0];
    const float* eWih = (const float*)d_in[1];
    const float* eWhh = (const float*)d_in[2];
    const float* eBih = (const float*)d_in[3];
    const float* eBhh = (const float*)d_in[4];
    const float* dWih = (const float*)d_in[5];
    const float* dWhh = (const float*)d_in[6];
    const float* dBih = (const float*)d_in[7];
    const float* dBhh = (const float*)d_in[8];
    const float* fcW  = (const float*)d_in[9];
    const float* fcB  = (const float*)d_in[10];
    float* out = (float*)d_out;

    const int B = in_sizes[0] / SEQ;    // 2048
    seq2seq_kernel<<<B / MB, 512, 0, stream>>>(src, eWih, eWhh, eBih, eBhh,
                                               dWih, dWhh, dBih, dBhh,
                                               fcW, fcB, out);
}

// Round 11
// 902.453 us; speedup vs baseline: 1.1213x; 1.1213x over previous
//
#include <hip/hip_runtime.h>

// Seq2Seq LSTM (enc 512 + dec 256 steps), H=50, B=2048, in/out dim 1.
//
// Round-11: MFMA with gate-complete waves. r10 proved bf16-split MFMA is
// numerically fine (absmax 4.9e-4) but was latency-bound: 1 block/CU, two
// barriers/step, gact LDS round-trip, 7.5e7 bank conflicts.
//
// New decomposition: block 256 thr = 4 waves = MB=4 batch elements.
// Wave w owns units 16w..16w+15 and computes ALL FOUR gates for them as 4
// MFMA accumulators sharing the same A (h) fragments:
//   Gates[g][4x16] = H[4(pad 16)x64] @ Whh[g]^T[64x16]   (16x16x32 bf16)
// D layout: col n = lane&15 = unit-in-tile, row m = (lane>>4)*4+r = batch.
// Lanes kg==0 hold i,f,g,o of cells (batch r, unit 16w+nl) in registers ->
// cell update IN-REGISTER, no gact buffer, ONE barrier per step.
// Weights: 2-way bf16 split (hi+lo), 3 cross terms (lo*lo dropped, ~2^-18
// rel) -> 24 MFMAs/wave-step; B-frags (16 short8) may live in AGPRs for
// free (MFMA reads AGPR operands natively -- the r10 premise, kept).
// h: 2-way split, 8 ds_write_b16 into 136-short-pitch blocks (bank stagger).
// MB=4 -> grid 512 = 2 blocks/CU: the other block hides barrier stalls.
// L2E folded into weights/bias (gate g doubled) -> sigm = rcp(1+exp2(-a)).

#define HID 50
#define SEQ 512
#define TGT 256
#define MB  4
#define L2E 1.44269504088896341f

typedef __attribute__((ext_vector_type(8))) short short8;
typedef __attribute__((ext_vector_type(4))) float f32x4;

__device__ __forceinline__ unsigned short f2bf(float f) {   // RNE fp32->bf16
    unsigned u = __float_as_uint(f);
    return (unsigned short)((u + 0x7fffu + ((u >> 16) & 1u)) >> 16);
}
__device__ __forceinline__ float bf2f(unsigned short b) {
    return __uint_as_float(((unsigned)b) << 16);
}
__device__ __forceinline__ float sigm2(float a) {   // a pre-scaled by L2E
    return __builtin_amdgcn_rcpf(1.0f + __builtin_amdgcn_exp2f(-a));
}
__device__ __forceinline__ float tanhc(float c) {   // c in linear domain
    return fmaf(2.0f,
        __builtin_amdgcn_rcpf(1.0f + __builtin_amdgcn_exp2f(-2.0f * L2E * c)),
        -1.0f);
}

#define MFMA(A, B, C) __builtin_amdgcn_mfma_f32_16x16x32_bf16((A), (B), (C), 0, 0, 0)

// h-fragment store: block (s,kt,qg) = 136 shorts (272B pitch: 16B-aligned,
// rotates banks by 4 per block). il = batch row m (0..15), j = k&7.
#define HFI(s, kt, qg, il, j) ((((s) * 2 + (kt)) * 4 + (qg)) * 136 + (il) * 8 + (j))
#define HFSZ (2 * 2 * 4 * 136)   // 2176 shorts

// One step: A-frags from HIN, 24 MFMAs, in-register cell update (kg==0
// lanes own cells), h 2-way split written to HOUT. Defines nothing outside;
// uses/updates cc[4], hh[4]. No barrier inside.
#define GCORE(X4, HIN, HOUT)                                           \
    {                                                                  \
        short8 a00 = *(const short8*)((HIN) + HFI(0, 0, kg, nl, 0));   \
        short8 a01 = *(const short8*)((HIN) + HFI(1, 0, kg, nl, 0));   \
        short8 a10 = *(const short8*)((HIN) + HFI(0, 1, kg, nl, 0));   \
        short8 a11 = *(const short8*)((HIN) + HFI(1, 1, kg, nl, 0));   \
        f32x4 ac[4];                                                   \
        _Pragma("unroll")                                              \
        for (int g = 0; g < 4; ++g)                                    \
            _Pragma("unroll")                                          \
            for (int r = 0; r < 4; ++r)                                \
                ac[g][r] = fmaf(wx[g], (X4)[r], bb[g]);                \
        _Pragma("unroll")                                              \
        for (int g = 0; g < 4; ++g) {                                  \
            ac[g] = MFMA(a00, Bf[g][0][0], ac[g]);   /* h0*w0 kt0 */   \
            ac[g] = MFMA(a00, Bf[g][0][1], ac[g]);   /* h0*w1 */       \
            ac[g] = MFMA(a01, Bf[g][0][0], ac[g]);   /* h1*w0 */       \
            ac[g] = MFMA(a10, Bf[g][1][0], ac[g]);   /* kt1 */         \
            ac[g] = MFMA(a10, Bf[g][1][1], ac[g]);                     \
            ac[g] = MFMA(a11, Bf[g][1][0], ac[g]);                     \
        }                                                              \
        if (kg == 0) {           /* rows m=0..3 = the 4 real batches */\
            _Pragma("unroll")                                          \
            for (int r = 0; r < 4; ++r) {                              \
                float vi = sigm2(ac[0][r]);                            \
                float vf = sigm2(ac[1][r]);                            \
                float vg = fmaf(2.0f, sigm2(ac[2][r]), -1.0f);         \
                float vo = sigm2(ac[3][r]);                            \
                cc[r] = fmaf(vf, cc[r], vi * vg);                      \
                hh[r] = vo * tanhc(cc[r]);                             \
            }                                                          \
            _Pragma("unroll")                                          \
            for (int r = 0; r < 4; ++r) {                              \
                unsigned short p0 = f2bf(hh[r]);                       \
                unsigned short p1 = f2bf(hh[r] - bf2f(p0));            \
                (HOUT)[HFI(0, ukt, uqg, r, uj)] = (short)p0;           \
                (HOUT)[HFI(1, ukt, uqg, r, uj)] = (short)p1;           \
            }                                                          \
        }                                                              \
    }

// Decoder step: GCORE + fc 16-lane butterfly -> pbuf, barrier, y broadcast,
// out write, feedback into xc.
#define DSTEP(T, HIN, HOUT, PB)                                        \
    {                                                                  \
        GCORE(xc, HIN, HOUT)                                           \
        if (kg == 0) {                                                 \
            float p0_ = fcw * hh[0], p1_ = fcw * hh[1];                \
            float p2_ = fcw * hh[2], p3_ = fcw * hh[3];                \
            _Pragma("unroll")                                          \
            for (int off = 1; off < 16; off <<= 1) {                   \
                p0_ += __shfl_xor(p0_, off, 64);                       \
                p1_ += __shfl_xor(p1_, off, 64);                       \
                p2_ += __shfl_xor(p2_, off, 64);                       \
                p3_ += __shfl_xor(p3_, off, 64);                       \
            }                                                          \
            if (lane == 0)                                             \
                *(f32x4*)&(PB)[4 * w] = (f32x4){p0_, p1_, p2_, p3_};   \
        }                                                              \
        __syncthreads();                                               \
        f32x4 y4 = *(const f32x4*)&(PB)[0];                            \
        y4 += *(const f32x4*)&(PB)[4];                                 \
        y4 += *(const f32x4*)&(PB)[8];                                 \
        y4 += *(const f32x4*)&(PB)[12];                                \
        _Pragma("unroll") for (int r = 0; r < 4; ++r) y4[r] += fb;     \
        if (tid < 4)                                                   \
            out[(size_t)(b0 + tid) * TGT + (T)] =                      \
                (tid == 0) ? y4[0] : (tid == 1) ? y4[1]                \
              : (tid == 2) ? y4[2] : y4[3];                            \
        xc = y4;                                                       \
    }

extern "C" __global__ void __launch_bounds__(256, 2)
seq2seq_kernel(const float* __restrict__ src,
               const float* __restrict__ eWih, const float* __restrict__ eWhh,
               const float* __restrict__ eBih, const float* __restrict__ eBhh,
               const float* __restrict__ dWih, const float* __restrict__ dWhh,
               const float* __restrict__ dBih, const float* __restrict__ dBhh,
               const float* __restrict__ fcW, const float* __restrict__ fcB,
               float* __restrict__ out) {
    const int tid  = threadIdx.x;        // 0..255
    const int lane = tid & 63;
    const int w    = tid >> 6;           // wave 0..3 = unit tile
    const int nl   = lane & 15;          // n-col within tile
    const int kg   = lane >> 4;          // k-group / D row-group
    const int un   = 16 * w + nl;        // global unit of my n-col
    const int ukt  = un >> 5, uqg = (un >> 3) & 3, uj = un & 7;
    const int b0   = blockIdx.x * MB;    // batch base

    __shared__ __align__(16) short hfA[HFSZ], hfB[HFSZ];  // h splits, dbuf
    __shared__ __align__(16) float srcT[SEQ * MB];        // [t][4 batches]
    __shared__ __align__(16) float pbA[16], pbB[16];      // fc partials

    for (int i = tid; i < HFSZ; i += 256) { hfA[i] = 0; hfB[i] = 0; }
    for (int i = tid; i < SEQ * MB; i += 256)
        srcT[i] = src[(size_t)(b0 + (i & 3)) * SEQ + (i >> 2)];

    short8 Bf[4][2][2];                  // [gate][kt][split] -- AGPR-friendly
    float bb[4], wx[4];
    float cc[4] = {0.f, 0.f, 0.f, 0.f};  // cells (batch r, unit un), kg==0
    float hh[4];

    auto loadW = [&](const float* Wih, const float* Whh,
                     const float* Bih, const float* Bhh) {
#pragma unroll
        for (int g = 0; g < 4; ++g) {
            const float sc = (g == 2) ? 2.0f * L2E : L2E;  // tanh fold
            const bool nv  = (un < HID);
            const int row  = g * HID + (nv ? un : 0);      // PyTorch g*50+u
            bb[g] = nv ? (Bih[row] + Bhh[row]) * sc : 0.0f;
            wx[g] = nv ? Wih[row] * sc : 0.0f;
#pragma unroll
            for (int kt = 0; kt < 2; ++kt) {
                short8 s0, s1;
#pragma unroll
                for (int j = 0; j < 8; ++j) {
                    int kk = kt * 32 + kg * 8 + j;
                    float wv = (nv && kk < HID)
                             ? Whh[(size_t)row * HID + kk] * sc : 0.0f;
                    unsigned short q0 = f2bf(wv);
                    unsigned short q1 = f2bf(wv - bf2f(q0));
                    s0[j] = (short)q0; s1[j] = (short)q1;
                }
                Bf[g][kt][0] = s0; Bf[g][kt][1] = s1;
            }
        }
    };

    // ---------------- encoder: 512 steps (x2 unroll) ----------------
    loadW(eWih, eWhh, eBih, eBhh);
    __syncthreads();                     // hf zero + srcT staged
    for (int t = 0; t < SEQ; t += 2) {
        { f32x4 x4 = *(const f32x4*)&srcT[4 * t];     GCORE(x4, hfA, hfB) }
        __syncthreads();
        { f32x4 x4 = *(const f32x4*)&srcT[4 * t + 4]; GCORE(x4, hfB, hfA) }
        __syncthreads();
    }
    // state in hfA

    // ---------------- decoder: 256 steps (x2 unroll) ----------------
    loadW(dWih, dWhh, dBih, dBhh);
    const float fcw = (kg == 0 && un < HID) ? fcW[un] : 0.0f;
    const float fb  = fcB[0];
    f32x4 xc = {0.f, 0.f, 0.f, 0.f};     // decoder_input = zeros
    for (int t = 0; t < TGT; t += 2) {
        DSTEP(t,     hfA, hfB, pbA)
        DSTEP(t + 1, hfB, hfA, pbB)
    }
}

extern "C" void kernel_launch(void* const* d_in, const int* in_sizes, int n_in,
                              void* d_out, int out_size, void* d_ws, size_t ws_size,
                              hipStream_t stream) {
    const float* src  = (const float*)d_in[0];
    const float* eWih = (const float*)d_in[1];
    const float* eWhh = (const float*)d_in[2];
    const float* eBih = (const float*)d_in[3];
    const float* eBhh = (const float*)d_in[4];
    const float* dWih = (const float*)d_in[5];
    const float* dWhh = (const float*)d_in[6];
    const float* dBih = (const float*)d_in[7];
    const float* dBhh = (const float*)d_in[8];
    const float* fcW  = (const float*)d_in[9];
    const float* fcB  = (const float*)d_in[10];
    float* out = (float*)d_out;

    const int B = in_sizes[0] / SEQ;     // 2048
    seq2seq_kernel<<<B / MB, 256, 0, stream>>>(src, eWih, eWhh, eBih, eBhh,
                                               dWih, dWhh, dBih, dBhh,
                                               fcW, fcB, out);
}

// Round 12
// 551.496 us; speedup vs baseline: 1.8349x; 1.6364x over previous
//
#include <hip/hip_runtime.h>

// Seq2Seq LSTM (enc 512 + dec 256 steps), H=50, B=2048, in/out dim 1.
//
// Round-12: r11's gate-complete-wave MFMA, M-dimension fixed. r11 (MB=4)
// wasted 3/4 of the MFMA rows AND ran activations on 16/64 lanes (40 trans
// instr per wave-step for 4 elements). Here MB=8 with DUPLICATED A-rows:
// A rows 8-15 re-read batches 0-7's h from LDS (m&7 -> free broadcast), so
// D rows 8-15 duplicate the gates; each kg-quad then owns 2 distinct cells:
//   kg0 -> batches {0,1} (rows 0,1)    kg1 -> {4,5} (rows 4,5)
//   kg2 -> batches {2,3} (rows 10,11)  kg3 -> {6,7} (rows 14,15)
// -> all 64 lanes do cell updates: 20 trans instr / 8 elements per step.
// Grid = 2048/8 = 256 blocks (1/CU), block = 4 waves (wave w = units
// 16w..16w+15, all 4 gates as 4 MFMA accumulators). ONE barrier per step.
// Decoder y: 16-lane butterfly -> pbuf[e][w]; after the barrier each lane
// rebuilds its 2 y's (broadcast b128) + partner-quad via shfl_xor(32) --
// no second barrier. 2-way bf16 weight/h split, 3 cross terms (r10/r11
// verified absmax 4.9e-4). L2E folded into weights/bias.

#define HID 50
#define SEQ 512
#define TGT 256
#define MB  8
#define L2E 1.44269504088896341f

typedef __attribute__((ext_vector_type(8))) short short8;
typedef __attribute__((ext_vector_type(4))) float f32x4;

__device__ __forceinline__ unsigned short f2bf(float f) {   // RNE fp32->bf16
    unsigned u = __float_as_uint(f);
    return (unsigned short)((u + 0x7fffu + ((u >> 16) & 1u)) >> 16);
}
__device__ __forceinline__ float bf2f(unsigned short b) {
    return __uint_as_float(((unsigned)b) << 16);
}
__device__ __forceinline__ float sigm2(float a) {   // a pre-scaled by L2E
    return __builtin_amdgcn_rcpf(1.0f + __builtin_amdgcn_exp2f(-a));
}
__device__ __forceinline__ float tanhc(float c) {   // c in linear domain
    return fmaf(2.0f,
        __builtin_amdgcn_rcpf(1.0f + __builtin_amdgcn_exp2f(-2.0f * L2E * c)),
        -1.0f);
}

#define MFMA(A, B, C) __builtin_amdgcn_mfma_f32_16x16x32_bf16((A), (B), (C), 0, 0, 0)

// h storage: block (split s, k-tile kt, k-octet qg) = 8 batches x 8 k
// shorts, padded to 72 shorts (144 B: 16B-aligned, rotates banks by 4).
#define HBLK 72
#define HFB(s, kt, qg) ((((s) * 2 + (kt)) * 4 + (qg)) * HBLK)
#define HFSZ (2 * 2 * 4 * HBLK)

// One step. Reads h state from HIN, writes new h splits to HOUT; defines
// hv0, hv1 (this lane's two cells); updates cc0, cc1. No barrier inside.
#define GCORE(X4, HIN, HOUT)                                           \
    float hv0, hv1;                                                    \
    {                                                                  \
        const short* hin_ = (HIN);                                     \
        short8 a00 = *(const short8*)(hin_ + HFB(0, 0, kg) + (lane & 7) * 8); \
        short8 a01 = *(const short8*)(hin_ + HFB(1, 0, kg) + (lane & 7) * 8); \
        short8 a10 = *(const short8*)(hin_ + HFB(0, 1, kg) + (lane & 7) * 8); \
        short8 a11 = *(const short8*)(hin_ + HFB(1, 1, kg) + (lane & 7) * 8); \
        f32x4 ac0, ac1, ac2, ac3;                                      \
        _Pragma("unroll")                                              \
        for (int r = 0; r < 4; ++r) {                                  \
            ac0[r] = fmaf(wx[0], (X4)[r], bb[0]);                      \
            ac1[r] = fmaf(wx[1], (X4)[r], bb[1]);                      \
            ac2[r] = fmaf(wx[2], (X4)[r], bb[2]);                      \
            ac3[r] = fmaf(wx[3], (X4)[r], bb[3]);                      \
        }                                                              \
        ac0 = MFMA(a00, Bf[0][0][0], ac0);                             \
        ac1 = MFMA(a00, Bf[1][0][0], ac1);                             \
        ac2 = MFMA(a00, Bf[2][0][0], ac2);                             \
        ac3 = MFMA(a00, Bf[3][0][0], ac3);                             \
        ac0 = MFMA(a00, Bf[0][0][1], ac0);                             \
        ac1 = MFMA(a00, Bf[1][0][1], ac1);                             \
        ac2 = MFMA(a00, Bf[2][0][1], ac2);                             \
        ac3 = MFMA(a00, Bf[3][0][1], ac3);                             \
        ac0 = MFMA(a01, Bf[0][0][0], ac0);                             \
        ac1 = MFMA(a01, Bf[1][0][0], ac1);                             \
        ac2 = MFMA(a01, Bf[2][0][0], ac2);                             \
        ac3 = MFMA(a01, Bf[3][0][0], ac3);                             \
        ac0 = MFMA(a10, Bf[0][1][0], ac0);                             \
        ac1 = MFMA(a10, Bf[1][1][0], ac1);                             \
        ac2 = MFMA(a10, Bf[2][1][0], ac2);                             \
        ac3 = MFMA(a10, Bf[3][1][0], ac3);                             \
        ac0 = MFMA(a10, Bf[0][1][1], ac0);                             \
        ac1 = MFMA(a10, Bf[1][1][1], ac1);                             \
        ac2 = MFMA(a10, Bf[2][1][1], ac2);                             \
        ac3 = MFMA(a10, Bf[3][1][1], ac3);                             \
        ac0 = MFMA(a11, Bf[0][1][0], ac0);                             \
        ac1 = MFMA(a11, Bf[1][1][0], ac1);                             \
        ac2 = MFMA(a11, Bf[2][1][0], ac2);                             \
        ac3 = MFMA(a11, Bf[3][1][0], ac3);                             \
        const bool hi_ = (kg & 2);   /* cell rows: regs {2,3} vs {0,1} */ \
        float gi0 = hi_ ? ac0[2] : ac0[0], gi1 = hi_ ? ac0[3] : ac0[1]; \
        float gf0 = hi_ ? ac1[2] : ac1[0], gf1 = hi_ ? ac1[3] : ac1[1]; \
        float gg0 = hi_ ? ac2[2] : ac2[0], gg1 = hi_ ? ac2[3] : ac2[1]; \
        float go0 = hi_ ? ac3[2] : ac3[0], go1 = hi_ ? ac3[3] : ac3[1]; \
        float vi0 = sigm2(gi0), vi1 = sigm2(gi1);                      \
        float vf0 = sigm2(gf0), vf1 = sigm2(gf1);                      \
        float vg0 = fmaf(2.0f, sigm2(gg0), -1.0f);                     \
        float vg1 = fmaf(2.0f, sigm2(gg1), -1.0f);                     \
        float vo0 = sigm2(go0), vo1 = sigm2(go1);                      \
        cc0 = fmaf(vf0, cc0, vi0 * vg0);                               \
        cc1 = fmaf(vf1, cc1, vi1 * vg1);                               \
        hv0 = vo0 * tanhc(cc0);                                        \
        hv1 = vo1 * tanhc(cc1);                                        \
        short* ho_ = (HOUT);                                           \
        unsigned short q0 = f2bf(hv0);                                 \
        unsigned short q1 = f2bf(hv0 - bf2f(q0));                      \
        unsigned short q2 = f2bf(hv1);                                 \
        unsigned short q3 = f2bf(hv1 - bf2f(q2));                      \
        ho_[wr00] = (short)q0;  ho_[wr01] = (short)q1;                 \
        ho_[wr10] = (short)q2;  ho_[wr11] = (short)q3;                 \
    }

// Decoder step: GCORE + fc butterfly -> pbuf; barrier; rebuild y in every
// lane (broadcast b128 + partner shfl), write out, assemble next x4.
#define DSTEP(T, HIN, HOUT, PB)                                        \
    {                                                                  \
        GCORE(xc, HIN, HOUT)                                           \
        float p0 = fcw * hv0, p1 = fcw * hv1;                          \
        p0 += __shfl_xor(p0, 1, 64);  p1 += __shfl_xor(p1, 1, 64);     \
        p0 += __shfl_xor(p0, 2, 64);  p1 += __shfl_xor(p1, 2, 64);     \
        p0 += __shfl_xor(p0, 4, 64);  p1 += __shfl_xor(p1, 4, 64);     \
        p0 += __shfl_xor(p0, 8, 64);  p1 += __shfl_xor(p1, 8, 64);     \
        if (nl == 0) { (PB)[e0 * 4 + w] = p0; (PB)[e0 * 4 + 4 + w] = p1; } \
        __syncthreads();                                               \
        f32x4 s0_ = *(const f32x4*)&(PB)[e0 * 4];                      \
        f32x4 s1_ = *(const f32x4*)&(PB)[e0 * 4 + 4];                  \
        float y0 = s0_[0] + s0_[1] + s0_[2] + s0_[3] + fb;             \
        float y1 = s1_[0] + s1_[1] + s1_[2] + s1_[3] + fb;             \
        if (w == 0 && nl == 0) {                                       \
            out[(size_t)(b0 + e0) * TGT + (T)] = y0;                   \
            out[(size_t)(b0 + e0 + 1) * TGT + (T)] = y1;               \
        }                                                              \
        float yp0 = __shfl_xor(y0, 32, 64);                            \
        float yp1 = __shfl_xor(y1, 32, 64);                            \
        xc = (kg < 2) ? (f32x4){y0, y1, yp0, yp1}                      \
                      : (f32x4){yp0, yp1, y0, y1};                     \
    }

extern "C" __global__ void __launch_bounds__(256, 1)
seq2seq_kernel(const float* __restrict__ src,
               const float* __restrict__ eWih, const float* __restrict__ eWhh,
               const float* __restrict__ eBih, const float* __restrict__ eBhh,
               const float* __restrict__ dWih, const float* __restrict__ dWhh,
               const float* __restrict__ dBih, const float* __restrict__ dBhh,
               const float* __restrict__ fcW, const float* __restrict__ fcB,
               float* __restrict__ out) {
    const int tid  = threadIdx.x;        // 0..255
    const int lane = tid & 63;
    const int w    = tid >> 6;           // wave 0..3 = unit tile
    const int nl   = lane & 15;          // n-col within tile
    const int kg   = lane >> 4;          // k-octet / D row-quad
    const int un   = 16 * w + nl;        // this lane's unit (B n-col)
    const int b0   = blockIdx.x * MB;
    // cells owned by this lane: batches e0, e0+1
    const int e0   = 4 * (kg & 1) + 2 * (kg >> 1);
    // h-write addresses (unit un, batches e0/e0+1, splits 0/1)
    const int ukt  = un >> 5, uqg = (un >> 3) & 3, uj = un & 7;
    const int wr00 = HFB(0, ukt, uqg) + e0 * 8 + uj;
    const int wr01 = HFB(1, ukt, uqg) + e0 * 8 + uj;
    const int wr10 = wr00 + 8;
    const int wr11 = wr01 + 8;

    __shared__ __align__(16) short hfA[HFSZ], hfB[HFSZ];   // h splits, dbuf
    __shared__ __align__(16) float srcT[SEQ * MB];         // [t][8 batches]
    __shared__ __align__(16) float pbA[64], pbB[64];       // fc partials [e][w]

    for (int i = tid; i < HFSZ; i += 256) { hfA[i] = 0; hfB[i] = 0; }
    for (int i = tid; i < SEQ * MB; i += 256) {
        int e = i >> 9, t = i & 511;                       // coalesced in t
        srcT[t * MB + e] = src[(size_t)(b0 + e) * SEQ + t];
    }

    short8 Bf[4][2][2];                  // [gate][kt][split] (AGPR-friendly)
    float bb[4], wx[4];
    float cc0 = 0.0f, cc1 = 0.0f;        // this lane's two cell states

    auto loadW = [&](const float* Wih, const float* Whh,
                     const float* Bih, const float* Bhh) {
#pragma unroll
        for (int g = 0; g < 4; ++g) {
            const float sc = (g == 2) ? 2.0f * L2E : L2E;  // tanh fold
            const bool nv  = (un < HID);
            const int row  = g * HID + (nv ? un : 0);      // PyTorch g*50+u
            bb[g] = nv ? (Bih[row] + Bhh[row]) * sc : 0.0f;
            wx[g] = nv ? Wih[row] * sc : 0.0f;
#pragma unroll
            for (int kt = 0; kt < 2; ++kt) {
                short8 s0, s1;
#pragma unroll
                for (int j = 0; j < 8; ++j) {
                    int kk = kt * 32 + kg * 8 + j;
                    float wv = (nv && kk < HID)
                             ? Whh[(size_t)row * HID + kk] * sc : 0.0f;
                    unsigned short h0 = f2bf(wv);
                    unsigned short h1 = f2bf(wv - bf2f(h0));
                    s0[j] = (short)h0; s1[j] = (short)h1;
                }
                Bf[g][kt][0] = s0; Bf[g][kt][1] = s1;
            }
        }
    };

    // ---------------- encoder: 512 steps (x2 unroll) ----------------
    loadW(eWih, eWhh, eBih, eBhh);
    __syncthreads();                     // hf zero + srcT staged
    for (int t = 0; t < SEQ; t += 2) {
        {
            f32x4 xe = *(const f32x4*)&srcT[t * MB + 4 * (kg & 1)];
            GCORE(xe, hfA, hfB)
        }
        __syncthreads();
        {
            f32x4 xe = *(const f32x4*)&srcT[(t + 1) * MB + 4 * (kg & 1)];
            GCORE(xe, hfB, hfA)
        }
        __syncthreads();
    }
    // state in hfA

    // ---------------- decoder: 256 steps (x2 unroll) ----------------
    loadW(dWih, dWhh, dBih, dBhh);
    const float fcw = (un < HID) ? fcW[un] : 0.0f;
    const float fb  = fcB[0];
    f32x4 xc = {0.f, 0.f, 0.f, 0.f};     // decoder_input = zeros
    for (int t = 0; t < TGT; t += 2) {
        DSTEP(t,     hfA, hfB, pbA)
        DSTEP(t + 1, hfB, hfA, pbB)
    }
}

extern "C" void kernel_launch(void* const* d_in, const int* in_sizes, int n_in,
                              void* d_out, int out_size, void* d_ws, size_t ws_size,
                              hipStream_t stream) {
    const float* src  = (const float*)d_in[0];
    const float* eWih = (const float*)d_in[1];
    const float* eWhh = (const float*)d_in[2];
    const float* eBih = (const float*)d_in[3];
    const float* eBhh = (const float*)d_in[4];
    const float* dWih = (const float*)d_in[5];
    const float* dWhh = (const float*)d_in[6];
    const float* dBih = (const float*)d_in[7];
    const float* dBhh = (const float*)d_in[8];
    const float* fcW  = (const float*)d_in[9];
    const float* fcB  = (const float*)d_in[10];
    float* out = (float*)d_out;

    const int B = in_sizes[0] / SEQ;     // 2048
    seq2seq_kernel<<<B / MB, 256, 0, stream>>>(src, eWih, eWhh, eBih, eBhh,
                                               dWih, dWhh, dBih, dBhh,
                                               fcW, fcB, out);
}

// Round 13
// 530.752 us; speedup vs baseline: 1.9066x; 1.0391x over previous
//
#include <hip/hip_runtime.h>

// Seq2Seq LSTM (enc 512 + dec 256 steps), H=50, B=2048, in/out dim 1.
//
// Round-13: r12 skeleton (gate-complete waves, one barrier/step, 2-way bf16
// split MFMA) at MB=4 with 2 blocks/CU. r12 (MB=8, 256 blocks) ran 1 wave/
// SIMD: 1640 cyc/step vs ~500 cyc of issue -- pure chain-latency exposure.
// MB=4 -> grid 512 = 2 blocks/CU = 2 waves/SIMD; the co-resident block's
// chain hides ours. r11's MB=4 flaw (cells on 16/64 lanes) is fixed by ROW
// DUPLICATION with a fixed-reg mapping: A-row m carries batch m>>2, so
// lane (kg,nl) finds batch kg's gates in REG 0 of each accumulator (no
// dynamic reg select), and all 64 lanes update exactly one cell
// (batch kg, unit un=16w+nl). h storage: 512 shorts/buffer; A-reads are
// 4-lane broadcasts (2-way bank alias = free), h-writes 64 distinct b16.
//
// Fragments (verified r10-r12, absmax 4.9e-4):
//   A[m=lane&15][k=kg*8+j]  B[n=nl][k=kt*32+kg*8+j]  D row=4*kg+r, col=nl.
// L2E folded into weights/bias (gate g doubled -> tanh via sigm).

#define HID 50
#define SEQ 512
#define TGT 256
#define MB  4
#define L2E 1.44269504088896341f

typedef __attribute__((ext_vector_type(8))) short short8;
typedef __attribute__((ext_vector_type(4))) float f32x4;

__device__ __forceinline__ unsigned short f2bf(float f) {   // RNE fp32->bf16
    unsigned u = __float_as_uint(f);
    return (unsigned short)((u + 0x7fffu + ((u >> 16) & 1u)) >> 16);
}
__device__ __forceinline__ float bf2f(unsigned short b) {
    return __uint_as_float(((unsigned)b) << 16);
}
__device__ __forceinline__ float sigm2(float a) {   // a pre-scaled by L2E
    return __builtin_amdgcn_rcpf(1.0f + __builtin_amdgcn_exp2f(-a));
}
__device__ __forceinline__ float tanhc(float c) {   // c in linear domain
    return fmaf(2.0f,
        __builtin_amdgcn_rcpf(1.0f + __builtin_amdgcn_exp2f(-2.0f * L2E * c)),
        -1.0f);
}

#define MFMA(A, B, C) __builtin_amdgcn_mfma_f32_16x16x32_bf16((A), (B), (C), 0, 0, 0)

// h layout: block (split s, k-tile kt, k-octet qg) = 4 batches x 8 k shorts.
#define HB(s, kt, qg) ((((s) * 2 + (kt)) * 4 + (qg)) * 32)
#define HFSZ (2 * 2 * 4 * 32)   // 512 shorts

// One step. XK = x for batch kg. Updates cc; defines hv; writes h splits.
#define GCORE(XK, HIN, HOUT)                                           \
    float hv;                                                          \
    {                                                                  \
        const short* hin_ = (HIN);                                     \
        short8 a00 = *(const short8*)(hin_ + HB(0, 0, kg) + bsel * 8); \
        short8 a01 = *(const short8*)(hin_ + HB(1, 0, kg) + bsel * 8); \
        short8 a10 = *(const short8*)(hin_ + HB(0, 1, kg) + bsel * 8); \
        short8 a11 = *(const short8*)(hin_ + HB(1, 1, kg) + bsel * 8); \
        float i0 = fmaf(wx[0], (XK), bb[0]);                           \
        float i1 = fmaf(wx[1], (XK), bb[1]);                           \
        float i2 = fmaf(wx[2], (XK), bb[2]);                           \
        float i3 = fmaf(wx[3], (XK), bb[3]);                           \
        f32x4 ac0 = {i0, i0, i0, i0};                                  \
        f32x4 ac1 = {i1, i1, i1, i1};                                  \
        f32x4 ac2 = {i2, i2, i2, i2};                                  \
        f32x4 ac3 = {i3, i3, i3, i3};                                  \
        ac0 = MFMA(a00, Bf[0][0][0], ac0);                             \
        ac1 = MFMA(a00, Bf[1][0][0], ac1);                             \
        ac2 = MFMA(a00, Bf[2][0][0], ac2);                             \
        ac3 = MFMA(a00, Bf[3][0][0], ac3);                             \
        ac0 = MFMA(a00, Bf[0][0][1], ac0);                             \
        ac1 = MFMA(a00, Bf[1][0][1], ac1);                             \
        ac2 = MFMA(a00, Bf[2][0][1], ac2);                             \
        ac3 = MFMA(a00, Bf[3][0][1], ac3);                             \
        ac0 = MFMA(a01, Bf[0][0][0], ac0);                             \
        ac1 = MFMA(a01, Bf[1][0][0], ac1);                             \
        ac2 = MFMA(a01, Bf[2][0][0], ac2);                             \
        ac3 = MFMA(a01, Bf[3][0][0], ac3);                             \
        ac0 = MFMA(a10, Bf[0][1][0], ac0);                             \
        ac1 = MFMA(a10, Bf[1][1][0], ac1);                             \
        ac2 = MFMA(a10, Bf[2][1][0], ac2);                             \
        ac3 = MFMA(a10, Bf[3][1][0], ac3);                             \
        ac0 = MFMA(a10, Bf[0][1][1], ac0);                             \
        ac1 = MFMA(a10, Bf[1][1][1], ac1);                             \
        ac2 = MFMA(a10, Bf[2][1][1], ac2);                             \
        ac3 = MFMA(a10, Bf[3][1][1], ac3);                             \
        ac0 = MFMA(a11, Bf[0][1][0], ac0);                             \
        ac1 = MFMA(a11, Bf[1][1][0], ac1);                             \
        ac2 = MFMA(a11, Bf[2][1][0], ac2);                             \
        ac3 = MFMA(a11, Bf[3][1][0], ac3);                             \
        float vi = sigm2(ac0[0]);                                      \
        float vf = sigm2(ac1[0]);                                      \
        float vg = fmaf(2.0f, sigm2(ac2[0]), -1.0f);                   \
        float vo = sigm2(ac3[0]);                                      \
        cc = fmaf(vf, cc, vi * vg);                                    \
        hv = vo * tanhc(cc);                                           \
        unsigned short q0 = f2bf(hv);                                  \
        unsigned short q1 = f2bf(hv - bf2f(q0));                       \
        short* ho_ = (HOUT);                                           \
        ho_[wr0] = (short)q0;                                          \
        ho_[wr1] = (short)q1;                                          \
    }

// Decoder step: GCORE + 16-lane fc butterfly -> pb; barrier; y rebuild in
// every lane; out write; feedback.
#define DSTEP(T, HIN, HOUT, PB)                                        \
    {                                                                  \
        GCORE(xc, HIN, HOUT)                                           \
        float p = fcw * hv;                                            \
        p += __shfl_xor(p, 1, 64);                                     \
        p += __shfl_xor(p, 2, 64);                                     \
        p += __shfl_xor(p, 4, 64);                                     \
        p += __shfl_xor(p, 8, 64);                                     \
        if (nl == 0) (PB)[kg * 4 + w] = p;                             \
        __syncthreads();                                               \
        f32x4 s_ = *(const f32x4*)&(PB)[kg * 4];                       \
        float y = s_[0] + s_[1] + s_[2] + s_[3] + fb;                  \
        if (w == 0 && nl == 0) out[(size_t)(b0 + kg) * TGT + (T)] = y; \
        xc = y;                                                        \
    }

extern "C" __global__ void __launch_bounds__(256, 2)
seq2seq_kernel(const float* __restrict__ src,
               const float* __restrict__ eWih, const float* __restrict__ eWhh,
               const float* __restrict__ eBih, const float* __restrict__ eBhh,
               const float* __restrict__ dWih, const float* __restrict__ dWhh,
               const float* __restrict__ dBih, const float* __restrict__ dBhh,
               const float* __restrict__ fcW, const float* __restrict__ fcB,
               float* __restrict__ out) {
    const int tid  = threadIdx.x;        // 0..255
    const int lane = tid & 63;
    const int w    = tid >> 6;           // wave 0..3 = unit tile
    const int nl   = lane & 15;          // n-col within tile
    const int kg   = lane >> 4;          // k-octet; ALSO this lane's batch
    const int bsel = nl >> 2;            // A-row m -> batch m>>2
    const int un   = 16 * w + nl;        // this lane's unit
    const int b0   = blockIdx.x * MB;
    const int ukt  = un >> 5, uqg = (un >> 3) & 3, uj = un & 7;
    const int wr0  = HB(0, ukt, uqg) + kg * 8 + uj;   // h split-0 write
    const int wr1  = HB(1, ukt, uqg) + kg * 8 + uj;   // h split-1 write

    __shared__ __align__(16) short hfA[HFSZ], hfB[HFSZ];  // h splits, dbuf
    __shared__ __align__(16) float srcT[SEQ * MB];        // [t][4 batches]
    __shared__ __align__(16) float pbA[16], pbB[16];      // fc partials [b][w]

    for (int i = tid; i < HFSZ; i += 256) { hfA[i] = 0; hfB[i] = 0; }
    for (int i = tid; i < SEQ * MB; i += 256) {
        int e = i >> 9, t = i & 511;                      // coalesced in t
        srcT[t * MB + e] = src[(size_t)(b0 + e) * SEQ + t];
    }

    short8 Bf[4][2][2];                  // [gate][kt][split] (AGPR-friendly)
    float bb[4], wx[4];
    float cc = 0.0f;                     // cell (batch kg, unit un)

    auto loadW = [&](const float* Wih, const float* Whh,
                     const float* Bih, const float* Bhh) {
#pragma unroll
        for (int g = 0; g < 4; ++g) {
            const float sc = (g == 2) ? 2.0f * L2E : L2E;  // tanh fold
            const bool nv  = (un < HID);
            const int row  = g * HID + (nv ? un : 0);      // PyTorch g*50+u
            bb[g] = nv ? (Bih[row] + Bhh[row]) * sc : 0.0f;
            wx[g] = nv ? Wih[row] * sc : 0.0f;
#pragma unroll
            for (int kt = 0; kt < 2; ++kt) {
                short8 s0, s1;
#pragma unroll
                for (int j = 0; j < 8; ++j) {
                    int kk = kt * 32 + kg * 8 + j;
                    float wv = (nv && kk < HID)
                             ? Whh[(size_t)row * HID + kk] * sc : 0.0f;
                    unsigned short h0 = f2bf(wv);
                    unsigned short h1 = f2bf(wv - bf2f(h0));
                    s0[j] = (short)h0; s1[j] = (short)h1;
                }
                Bf[g][kt][0] = s0; Bf[g][kt][1] = s1;
            }
        }
    };

    // ---------------- encoder: 512 steps (x2 unroll) ----------------
    loadW(eWih, eWhh, eBih, eBhh);
    __syncthreads();                     // hf zero + srcT staged
    for (int t = 0; t < SEQ; t += 2) {
        { GCORE(srcT[t * MB + kg], hfA, hfB) }
        __syncthreads();
        { GCORE(srcT[(t + 1) * MB + kg], hfB, hfA) }
        __syncthreads();
    }
    // state in hfA

    // ---------------- decoder: 256 steps (x2 unroll) ----------------
    loadW(dWih, dWhh, dBih, dBhh);
    const float fcw = (un < HID) ? fcW[un] : 0.0f;
    const float fb  = fcB[0];
    float xc = 0.0f;                     // decoder_input = zeros
    for (int t = 0; t < TGT; t += 2) {
        DSTEP(t,     hfA, hfB, pbA)
        DSTEP(t + 1, hfB, hfA, pbB)
    }
}

extern "C" void kernel_launch(void* const* d_in, const int* in_sizes, int n_in,
                              void* d_out, int out_size, void* d_ws, size_t ws_size,
                              hipStream_t stream) {
    const float* src  = (const float*)d_in[0];
    const float* eWih = (const float*)d_in[1];
    const float* eWhh = (const float*)d_in[2];
    const float* eBih = (const float*)d_in[3];
    const float* eBhh = (const float*)d_in[4];
    const float* dWih = (const float*)d_in[5];
    const float* dWhh = (const float*)d_in[6];
    const float* dBih = (const float*)d_in[7];
    const float* dBhh = (const float*)d_in[8];
    const float* fcW  = (const float*)d_in[9];
    const float* fcB  = (const float*)d_in[10];
    float* out = (float*)d_out;

    const int B = in_sizes[0] / SEQ;     // 2048
    seq2seq_kernel<<<B / MB, 256, 0, stream>>>(src, eWih, eWhh, eBih, eBhh,
                                               dWih, dWhh, dBih, dBhh,
                                               fcW, fcB, out);
}